// Round 16
// baseline (152.763 us; speedup 1.0000x reference)
//
#include <hip/hip_runtime.h>
#include <cstdint>

typedef unsigned long long u64;
typedef unsigned int u32;

#define WPRE 400
#define MIN_SCORE 0.01f
#define MAX_OVERLAP 0.45f
#define INV32 0x407FFFFFu   // f32_key(-1.0f)

// Exact predicate: fdiv_rn(inter,uniC) > 0.45f  <=>  (double)inter > MID*(double)uniC
// MID = midpoint(0.45f, nextafterf(0.45f,+inf)) = 0x1.CCCCCDp-2 (exact double).
#define IOU_MID 0x1.CCCCCDp-2

__device__ __forceinline__ u32 f32_key(float f) {
    u32 u = __float_as_uint(f);
    return (f >= 0.0f) ? (u | 0x80000000u) : ~u;
}
__device__ __forceinline__ float key_f32(u32 k) {
    return __uint_as_float((k & 0x80000000u) ? (k ^ 0x80000000u) : ~k);
}

struct SelSt {
    u64 prefix, thr;
    int r, above, shift, nge, done;
    u32 wtot[16];
};

// Exact top-K threshold over unique u64 keys (descending) via 1024-bin
// histogram level-descent. bulk: value sharing bits [63:14] with a large
// clump of keys (register-counted, one LDS atomic per wave per pass).
template <int T, typename KF>
__device__ void hist_select64(KF kf, int N, int K, int CAP, u64 bulk,
                              int tid, u32* hist, SelSt* st)
{
    const int lane = tid & 63;
    const int wv = tid >> 6;
    const int nw = T >> 6;
    constexpr int BPT = 1024 / T;

    if (tid == 0) { st->prefix = 0ull; st->r = K; st->above = 0; st->shift = 54; st->done = 0; }
    __syncthreads();

    while (true) {
        const int shift = st->shift;
        const u64 pref = st->prefix;
        const int r = st->r;
        const int above = st->above;
        const bool lvl0 = (shift == 54);
        #pragma unroll
        for (int q = 0; q < BPT; ++q) hist[tid * BPT + q] = 0u;
        __syncthreads();

        const bool useBulk = (bulk != 0ull) && (shift >= 14);
        const u64 bulkHi = bulk >> 14;
        u32 bulkCnt = 0;
        for (int i = tid; i < N; i += T) {
            u64 k;
            if (!kf(i, k)) continue;
            if (!lvl0 && (k >> (shift + 10)) != pref) continue;
            if (useBulk && (k >> 14) == bulkHi) { ++bulkCnt; continue; }
            atomicAdd(&hist[(u32)(k >> shift) & 1023u], 1u);
        }
        if (useBulk) {
            #pragma unroll
            for (int off = 32; off > 0; off >>= 1) bulkCnt += __shfl_down(bulkCnt, off, 64);
            if (lane == 0 && bulkCnt) atomicAdd(&hist[(u32)(bulk >> shift) & 1023u], bulkCnt);
        }
        __syncthreads();

        // block suffix-scan over 1024 bins (thread t owns bins [t*BPT, ...))
        u32 hloc[BPT], Sarr[BPT];
        u32 run = 0;
        #pragma unroll
        for (int q = BPT - 1; q >= 0; --q) {
            hloc[q] = hist[tid * BPT + q];
            run += hloc[q];
            Sarr[q] = run;
        }
        u32 incl = run;
        #pragma unroll
        for (int off = 1; off < 64; off <<= 1) {
            u32 x = __shfl_down(incl, off, 64);
            incl += (lane + off < 64) ? x : 0u;
        }
        if (lane == 0) st->wtot[wv] = incl;
        __syncthreads();
        u32 wa = 0;
        for (int w2 = wv + 1; w2 < nw; ++w2) wa += st->wtot[w2];
        const u32 suffAbove = wa + (incl - run);

        bool found = false; int fb = 0; u32 fSn = 0, fh = 0;
        #pragma unroll
        for (int q = 0; q < BPT; ++q) {
            u32 S = suffAbove + Sarr[q];
            u32 Sn = S - hloc[q];
            if ((int)S >= r && (int)Sn < r) { found = true; fb = tid * BPT + q; fSn = Sn; fh = hloc[q]; }
        }
        __syncthreads();
        if (found) {
            u64 np = (pref << 10) | (u64)(u32)fb;
            int nab = above + (int)fSn;
            int nge = nab + (int)fh;
            st->prefix = np;
            st->r = r - (int)fSn;
            st->above = nab;
            st->nge = nge;
            st->thr = np << shift;
            st->shift = shift - 10;
            st->done = (nge <= CAP) || (shift == 4);
        }
        __syncthreads();
        if (st->done) break;
    }
}

// Variant with SCORE-WORD bulk test: catches the -1 clump regardless of the
// index bits (needed when N > 16384 so ~idx spans multiple [31:14] patterns).
// Exact because the descent prefix always follows real scores (> MIN_SCORE),
// so -1 keys are prefix-filtered before the bulk test on all levels > 0, and
// at level 0 all -1 keys share the score-derived bin.
template <int T, typename KF>
__device__ void hist_select64_sc(KF kf, int N, int K, int CAP, u64 bulk,
                                 int tid, u32* hist, SelSt* st)
{
    const int lane = tid & 63;
    const int wv = tid >> 6;
    const int nw = T >> 6;
    constexpr int BPT = 1024 / T;
    const u32 bulkScore = (u32)(bulk >> 32);

    if (tid == 0) { st->prefix = 0ull; st->r = K; st->above = 0; st->shift = 54; st->done = 0; }
    __syncthreads();

    while (true) {
        const int shift = st->shift;
        const u64 pref = st->prefix;
        const int r = st->r;
        const int above = st->above;
        const bool lvl0 = (shift == 54);
        #pragma unroll
        for (int q = 0; q < BPT; ++q) hist[tid * BPT + q] = 0u;
        __syncthreads();

        u32 bulkCnt = 0;
        for (int i = tid; i < N; i += T) {
            u64 k;
            if (!kf(i, k)) continue;
            if (!lvl0 && (k >> (shift + 10)) != pref) continue;
            if ((u32)(k >> 32) == bulkScore) { ++bulkCnt; continue; }
            atomicAdd(&hist[(u32)(k >> shift) & 1023u], 1u);
        }
        {
            #pragma unroll
            for (int off = 32; off > 0; off >>= 1) bulkCnt += __shfl_down(bulkCnt, off, 64);
            if (lane == 0 && bulkCnt) atomicAdd(&hist[(u32)(bulk >> shift) & 1023u], bulkCnt);
        }
        __syncthreads();

        u32 hloc[BPT], Sarr[BPT];
        u32 run = 0;
        #pragma unroll
        for (int q = BPT - 1; q >= 0; --q) {
            hloc[q] = hist[tid * BPT + q];
            run += hloc[q];
            Sarr[q] = run;
        }
        u32 incl = run;
        #pragma unroll
        for (int off = 1; off < 64; off <<= 1) {
            u32 x = __shfl_down(incl, off, 64);
            incl += (lane + off < 64) ? x : 0u;
        }
        if (lane == 0) st->wtot[wv] = incl;
        __syncthreads();
        u32 wa = 0;
        for (int w2 = wv + 1; w2 < nw; ++w2) wa += st->wtot[w2];
        const u32 suffAbove = wa + (incl - run);

        bool found = false; int fb = 0; u32 fSn = 0, fh = 0;
        #pragma unroll
        for (int q = 0; q < BPT; ++q) {
            u32 S = suffAbove + Sarr[q];
            u32 Sn = S - hloc[q];
            if ((int)S >= r && (int)Sn < r) { found = true; fb = tid * BPT + q; fSn = Sn; fh = hloc[q]; }
        }
        __syncthreads();
        if (found) {
            u64 np = (pref << 10) | (u64)(u32)fb;
            int nab = above + (int)fSn;
            int nge = nab + (int)fh;
            st->prefix = np;
            st->r = r - (int)fSn;
            st->above = nab;
            st->nge = nge;
            st->thr = np << shift;
            st->shift = shift - 10;
            st->done = (nge <= CAP) || (shift == 4);
        }
        __syncthreads();
        if (st->done) break;
    }
}

// ---------------- Kernel 1: decode boxes + softmax ----------------
__global__ __launch_bounds__(256) void decode_softmax_kernel(
    const float* __restrict__ locs, const float* __restrict__ scores,
    const float* __restrict__ priors, float* __restrict__ dec,
    float* __restrict__ probs_t, int P, int C, int NC)
{
    __shared__ float tile[64 * 81];
    __shared__ float mrow[64], srow[64];
    const int b  = blockIdx.y;
    const int p0 = blockIdx.x * 64;
    const int tid = threadIdx.x;
    const int nrows = min(64, P - p0);
    const int n = nrows * C;

    const float* src = scores + ((size_t)b * P + p0) * C;
    for (int idx = tid; idx < n; idx += 256) tile[idx] = src[idx];

    if (tid < nrows) {
        int p = p0 + tid;
        float4 lc = ((const float4*)locs)[(size_t)b * P + p];
        float4 pr = ((const float4*)priors)[p];
        float cx = lc.x * pr.z / 10.0f + pr.x;
        float cy = lc.y * pr.w / 10.0f + pr.y;
        float w  = expf(lc.z / 5.0f) * pr.z;
        float h  = expf(lc.w / 5.0f) * pr.w;
        ((float4*)dec)[(size_t)b * P + p] =
            make_float4(cx - w * 0.5f, cy - h * 0.5f, cx + w * 0.5f, cy + h * 0.5f);
    }
    __syncthreads();

    if (tid < nrows) {
        const float* row = &tile[tid * C];
        float m = row[0];
        for (int cc = 1; cc < C; ++cc) m = fmaxf(m, row[cc]);
        float ss = 0.f;
        for (int cc = 0; cc < C; ++cc) ss += expf(row[cc] - m);
        mrow[tid] = m; srow[tid] = ss;
    }
    __syncthreads();

    for (int idx = tid; idx < 64 * NC; idx += 256) {
        int r  = idx & 63;
        int cc = idx >> 6;
        if (r < nrows) {
            float v = expf(tile[r * C + cc + 1] - mrow[r]) / srow[r];
            probs_t[((size_t)(b * NC + cc)) * P + p0 + r] = v;
        }
    }
}

// ------- Kernel 2: fused per (class,image) top-400 select + sort + IoU + NMS scan -------
// Byte-identical to the proven 131 us round-15 kernel.
__global__ __launch_bounds__(512) void select_nms_kernel(
    const float* __restrict__ dec, const float* __restrict__ probs_t,
    float* __restrict__ cand_sc, float* __restrict__ cand_bx,
    int P, int NC)
{
    const int c = blockIdx.x, b = blockIdx.y;
    const int tid = threadIdx.x;
    const int lane = tid & 63;
    const int wv = tid >> 6;
    const int T = 512;

    __shared__ alignas(16) char bufA[8736 * 4];
    u32* skey = (u32*)bufA;
    u64* inw  = (u64*)bufA;                       // [w][r][lane] column words, [0, 25088)
    float4* cbox = (float4*)(bufA + 25088);       // 448 * 16 B = [25088, 32256)
    __shared__ u64 cand[512];                     // hist[1024] aliases cand
    u32* hist = (u32*)cand;
    __shared__ u64 validm[7], keepm[7];
    __shared__ SelSt st;
    __shared__ int sh_cnt;

    const float* ps = probs_t + ((size_t)(b * NC + c)) * P;

    int P4 = P >> 2;
    for (int i = tid; i < P4; i += T) {
        float4 f4 = ((const float4*)ps)[i];
        skey[i*4+0] = f32_key(f4.x > MIN_SCORE ? f4.x : -1.0f);
        skey[i*4+1] = f32_key(f4.y > MIN_SCORE ? f4.y : -1.0f);
        skey[i*4+2] = f32_key(f4.z > MIN_SCORE ? f4.z : -1.0f);
        skey[i*4+3] = f32_key(f4.w > MIN_SCORE ? f4.w : -1.0f);
    }
    for (int i = (P4 << 2) + tid; i < P; i += T) {
        float f = ps[i];
        skey[i] = f32_key(f > MIN_SCORE ? f : -1.0f);
    }
    if (tid == 0) sh_cnt = 0;
    __syncthreads();

    hist_select64<512>([&](int i, u64& k) {
                           k = ((u64)skey[i] << 32) | (u64)(u32)(~(u32)i);
                           return true;
                       },
                       P, WPRE, 512, (((u64)INV32) << 32) | 0xFFFFFFFFull,
                       tid, hist, &st);
    const u64 thr = st.thr;

    for (int i = tid; i < P; i += T) {
        u64 k = ((u64)skey[i] << 32) | (u64)(u32)(~(u32)i);
        if (k >= thr) {
            int pos = atomicAdd(&sh_cnt, 1);
            if (pos < 512) cand[pos] = k;
        }
    }
    __syncthreads();
    const int cnt = sh_cnt;
    u64 v = (tid < cnt) ? cand[tid] : 0ull;

    for (int k = 2; k <= 512; k <<= 1) {
        for (int j = k >> 1; j > 0; j >>= 1) {
            u64 p;
            if (j < 64) {
                p = __shfl_xor(v, j, 64);
            } else {
                __syncthreads();
                cand[tid] = v;
                __syncthreads();
                p = cand[tid ^ j];
            }
            bool takeMax = (((tid & k) == 0) == ((tid & j) == 0));
            v = takeMax ? (v > p ? v : p) : (v > p ? p : v);
        }
    }
    __syncthreads();

    float4 mybox = make_float4(0.f, 0.f, 0.f, 0.f);
    float myval = -1.0f;
    if (tid < 448) {
        if (tid < WPRE) {
            myval = key_f32((u32)(v >> 32));
            int p = (int)(~(u32)v);
            mybox = ((const float4*)dec)[(size_t)b * P + p];
        }
        cbox[tid] = mybox;
        u64 mk = __ballot(myval > MIN_SCORE);
        if (lane == 0) validm[tid >> 6] = mk;
    }
    __syncthreads();

    for (int tt = wv; tt < 28; tt += 8) {
        int r = 0, base = 0;
        while (tt - base >= 7 - r) { base += 7 - r; ++r; }
        int w = r + (tt - base);
        int j = (w << 6) + lane;
        float4 bj = cbox[j];
        float aj = (bj.z - bj.x) * (bj.w - bj.y);
        const int i0 = r << 6;
        u32 acc0 = 0u, acc1 = 0u;
        #pragma unroll 16
        for (int q = 0; q < 32; ++q) {
            int i = i0 + q;
            float4 bi = cbox[i];
            float ai = (bi.z - bi.x) * (bi.w - bi.y);
            float lx = fmaxf(bi.x, bj.x);
            float ly = fmaxf(bi.y, bj.y);
            float rx = fminf(bi.z, bj.z);
            float ry = fminf(bi.w, bj.w);
            float ww = fmaxf(rx - lx, 0.f);
            float hh = fmaxf(ry - ly, 0.f);
            float inter = ww * hh;
            float uniC = fmaxf((ai + aj) - inter, 1e-10f);
            bool pred = (double)inter > IOU_MID * (double)uniC;
            acc0 |= pred ? (1u << q) : 0u;
        }
        #pragma unroll 16
        for (int q = 0; q < 32; ++q) {
            int i = i0 + 32 + q;
            float4 bi = cbox[i];
            float ai = (bi.z - bi.x) * (bi.w - bi.y);
            float lx = fmaxf(bi.x, bj.x);
            float ly = fmaxf(bi.y, bj.y);
            float rx = fminf(bi.z, bj.z);
            float ry = fminf(bi.w, bj.w);
            float ww = fmaxf(rx - lx, 0.f);
            float hh = fmaxf(ry - ly, 0.f);
            float inter = ww * hh;
            float uniC = fmaxf((ai + aj) - inter, 1e-10f);
            bool pred = (double)inter > IOU_MID * (double)uniC;
            acc1 |= pred ? (1u << q) : 0u;
        }
        inw[(w * 7 + r) * 64 + lane] = ((u64)acc1 << 32) | acc0;
    }
    __syncthreads();

    if (wv == 0) {
        u64 keep[7];
        #pragma unroll
        for (int w2 = 0; w2 < 7; ++w2) {
            bool alive = ((validm[w2] >> lane) & 1ull) != 0;
            #pragma unroll
            for (int r = 0; r < w2; ++r) {
                u64 inr = inw[(w2 * 7 + r) * 64 + lane];
                alive = alive && ((inr & keep[r]) == 0ull);
            }
            u64 in_self = inw[(w2 * 7 + w2) * 64 + lane];
            u64 inmask = in_self & ((1ull << lane) - 1ull);
            u64 mm = inmask;
            #pragma unroll
            for (int off = 32; off; off >>= 1) mm |= __shfl_xor(mm, off, 64);
            while (mm) {
                int t = __builtin_ctzll(mm);
                mm &= mm - 1ull;
                u64 am = __ballot(alive);
                if ((am >> t) & 1ull)
                    alive = alive && (((inmask >> t) & 1ull) == 0ull);
            }
            u64 fin = __ballot(alive);
            keep[w2] = fin;
            if (lane == 0) keepm[w2] = fin;
        }
    }
    __syncthreads();

    if (tid < WPRE) {
        bool keep = (keepm[tid >> 6] >> (tid & 63)) & 1ull;
        cand_sc[((size_t)(b * NC + c)) * WPRE + tid] = keep ? myval : -1.0f;
        ((float4*)cand_bx)[((size_t)(b * NC + c)) * WPRE + tid] = mybox;
    }
}

// ---------------- Kernel 3: fused per-image exact top-200 + emit ----------------
// One block per image, 1024 threads. Keys recomputed from global per pass
// (no 125 KB LDS staging); -1 flood handled by the score-word bulk path.
__global__ __launch_bounds__(1024) void topk_fused_kernel(
    const float* __restrict__ cand_sc, const float* __restrict__ cand_bx,
    float* __restrict__ out, int NC, int TOPK, int B)
{
    const int b = blockIdx.x;
    const int tid = threadIdx.x;
    const int T = 1024;
    const int N = NC * WPRE;          // 32000

    __shared__ u32 hist[1024];
    __shared__ u64 cand[256];
    __shared__ SelSt st;
    __shared__ int sh_cnt;

    const float* s = cand_sc + (size_t)b * N;
    if (tid == 0) sh_cnt = 0;
    __syncthreads();

    hist_select64_sc<1024>([&](int i, u64& k) {
                               k = ((u64)f32_key(s[i]) << 32) | (u64)(u32)(~(u32)i);
                               return true;
                           },
                           N, TOPK, 256, (((u64)INV32) << 32) | 0xFFFFFFFFull,
                           tid, hist, &st);
    const u64 thr = st.thr;

    for (int i = tid; i < N; i += T) {
        u64 k = ((u64)f32_key(s[i]) << 32) | (u64)(u32)(~(u32)i);
        if (k >= thr) {
            int pos = atomicAdd(&sh_cnt, 1);
            if (pos < 256) cand[pos] = k;
        }
    }
    __syncthreads();
    int cnt = sh_cnt;                 // nge in [TOPK, 256]
    u64 v = (tid < 256 && tid < cnt) ? cand[tid] : 0ull;

    // register bitonic sort 256 desc (waves 0-3 carry data; all hit barriers)
    for (int k = 2; k <= 256; k <<= 1) {
        for (int j = k >> 1; j > 0; j >>= 1) {
            u64 p;
            if (j < 64) {
                p = __shfl_xor(v, j, 64);
            } else {
                __syncthreads();
                if (tid < 256) cand[tid] = v;
                __syncthreads();
                p = (tid < 256) ? cand[tid ^ j] : 0ull;
            }
            bool takeMax = (((tid & k) == 0) == ((tid & j) == 0));
            v = takeMax ? (v > p ? v : p) : (v > p ? p : v);
        }
    }

    if (tid < TOPK) {
        float sc = key_f32((u32)(v >> 32));
        int flat = (int)(~(u32)v);
        int cls = flat / WPRE;
        float4 bx = ((const float4*)cand_bx)[(size_t)b * N + flat];
        float* ob = out + ((size_t)(b * TOPK + tid)) * 4;
        ob[0] = bx.x; ob[1] = bx.y; ob[2] = bx.z; ob[3] = bx.w;
        out[(size_t)B * TOPK * 4 + (size_t)b * TOPK + tid] = (float)(cls + 1);
        out[(size_t)B * TOPK * 5 + (size_t)b * TOPK + tid] = sc;
    }
}

extern "C" void kernel_launch(void* const* d_in, const int* in_sizes, int n_in,
                              void* d_out, int out_size, void* d_ws, size_t ws_size,
                              hipStream_t stream) {
    const float* locs   = (const float*)d_in[0];
    const float* scores = (const float*)d_in[1];
    const float* priors = (const float*)d_in[2];

    const int P  = in_sizes[2] / 4;          // 8732
    const int B  = in_sizes[0] / (4 * P);    // 8
    const int C  = in_sizes[1] / (B * P);    // 81
    const int NC = C - 1;                    // 80
    const int TOPK = out_size / (B * 6);     // 200

    float* ws      = (float*)d_ws;
    float* dec     = ws;                                    // B*P*4
    float* probs_t = dec + (size_t)B * P * 4;               // B*NC*P
    float* cand_sc = probs_t + (size_t)B * NC * P;          // B*NC*WPRE
    float* cand_bx = cand_sc + (size_t)B * NC * WPRE;       // B*NC*WPRE*4

    dim3 g1((P + 63) / 64, B);
    decode_softmax_kernel<<<g1, 256, 0, stream>>>(locs, scores, priors, dec, probs_t, P, C, NC);

    dim3 g2(NC, B);
    select_nms_kernel<<<g2, 512, 0, stream>>>(dec, probs_t, cand_sc, cand_bx, P, NC);

    topk_fused_kernel<<<dim3(B), 1024, 0, stream>>>(cand_sc, cand_bx, (float*)d_out, NC, TOPK, B);
}

// Round 17
// 128.392 us; speedup vs baseline: 1.1898x; 1.1898x over previous
//
#include <hip/hip_runtime.h>
#include <cstdint>

typedef unsigned long long u64;
typedef unsigned int u32;

#define WPRE 400
#define MIN_SCORE 0.01f
#define MAX_OVERLAP 0.45f
#define INV32 0x407FFFFFu   // f32_key(-1.0f)

// Exact predicate: fdiv_rn(inter,uniC) > 0.45f  <=>  (double)inter > MID*(double)uniC
// MID = midpoint(0.45f, nextafterf(0.45f,+inf)) = 0x1.CCCCCDp-2 (exact double).
#define IOU_MID 0x1.CCCCCDp-2

__device__ __forceinline__ u32 f32_key(float f) {
    u32 u = __float_as_uint(f);
    return (f >= 0.0f) ? (u | 0x80000000u) : ~u;
}
__device__ __forceinline__ float key_f32(u32 k) {
    return __uint_as_float((k & 0x80000000u) ? (k ^ 0x80000000u) : ~k);
}

struct SelSt {
    u64 prefix, thr;
    int r, above, shift, nge, done;
    u32 wtot[8];
};

// Exact top-K threshold over unique u64 keys (descending) via 1024-bin
// histogram level-descent. bulk: value sharing bits [63:14] with a large
// clump of keys (register-counted, one LDS atomic per wave per pass).
// PRE: level-0 histogram was prefilled by the caller (fused with staging);
// skip zero+count on the first level only. PRE=false compiles to the
// proven round-15 code path.
template <int T, bool PRE, typename KF>
__device__ void hist_select64(KF kf, int N, int K, int CAP, u64 bulk,
                              int tid, u32* hist, SelSt* st)
{
    const int lane = tid & 63;
    const int wv = tid >> 6;
    const int nw = T >> 6;
    constexpr int BPT = 1024 / T;

    if (tid == 0) { st->prefix = 0ull; st->r = K; st->above = 0; st->shift = 54; st->done = 0; }
    __syncthreads();

    while (true) {
        const int shift = st->shift;
        const u64 pref = st->prefix;
        const int r = st->r;
        const int above = st->above;
        const bool lvl0 = (shift == 54);

        if (!(PRE && lvl0)) {
            #pragma unroll
            for (int q = 0; q < BPT; ++q) hist[tid * BPT + q] = 0u;
            __syncthreads();

            const bool useBulk = (bulk != 0ull) && (shift >= 14);
            const u64 bulkHi = bulk >> 14;
            u32 bulkCnt = 0;
            for (int i = tid; i < N; i += T) {
                u64 k;
                if (!kf(i, k)) continue;
                if (!lvl0 && (k >> (shift + 10)) != pref) continue;
                if (useBulk && (k >> 14) == bulkHi) { ++bulkCnt; continue; }
                atomicAdd(&hist[(u32)(k >> shift) & 1023u], 1u);
            }
            if (useBulk) {
                #pragma unroll
                for (int off = 32; off > 0; off >>= 1) bulkCnt += __shfl_down(bulkCnt, off, 64);
                if (lane == 0 && bulkCnt) atomicAdd(&hist[(u32)(bulk >> shift) & 1023u], bulkCnt);
            }
            __syncthreads();
        }

        // block suffix-scan over 1024 bins (thread t owns bins [t*BPT, ...))
        u32 hloc[BPT], Sarr[BPT];
        u32 run = 0;
        #pragma unroll
        for (int q = BPT - 1; q >= 0; --q) {
            hloc[q] = hist[tid * BPT + q];
            run += hloc[q];
            Sarr[q] = run;
        }
        u32 incl = run;
        #pragma unroll
        for (int off = 1; off < 64; off <<= 1) {
            u32 x = __shfl_down(incl, off, 64);
            incl += (lane + off < 64) ? x : 0u;
        }
        if (lane == 0) st->wtot[wv] = incl;
        __syncthreads();
        u32 wa = 0;
        for (int w2 = wv + 1; w2 < nw; ++w2) wa += st->wtot[w2];
        const u32 suffAbove = wa + (incl - run);

        bool found = false; int fb = 0; u32 fSn = 0, fh = 0;
        #pragma unroll
        for (int q = 0; q < BPT; ++q) {
            u32 S = suffAbove + Sarr[q];
            u32 Sn = S - hloc[q];
            if ((int)S >= r && (int)Sn < r) { found = true; fb = tid * BPT + q; fSn = Sn; fh = hloc[q]; }
        }
        __syncthreads();
        if (found) {
            u64 np = (pref << 10) | (u64)(u32)fb;
            int nab = above + (int)fSn;
            int nge = nab + (int)fh;
            st->prefix = np;
            st->r = r - (int)fSn;
            st->above = nab;
            st->nge = nge;
            st->thr = np << shift;
            st->shift = shift - 10;
            st->done = (nge <= CAP) || (shift == 4);
        }
        __syncthreads();
        if (st->done) break;
    }
}

// ---------------- Kernel 1: decode boxes + softmax ----------------
__global__ __launch_bounds__(256) void decode_softmax_kernel(
    const float* __restrict__ locs, const float* __restrict__ scores,
    const float* __restrict__ priors, float* __restrict__ dec,
    float* __restrict__ probs_t, int P, int C, int NC)
{
    __shared__ float tile[64 * 81];
    __shared__ float mrow[64], srow[64];
    const int b  = blockIdx.y;
    const int p0 = blockIdx.x * 64;
    const int tid = threadIdx.x;
    const int nrows = min(64, P - p0);
    const int n = nrows * C;

    const float* src = scores + ((size_t)b * P + p0) * C;
    for (int idx = tid; idx < n; idx += 256) tile[idx] = src[idx];

    if (tid < nrows) {
        int p = p0 + tid;
        float4 lc = ((const float4*)locs)[(size_t)b * P + p];
        float4 pr = ((const float4*)priors)[p];
        float cx = lc.x * pr.z / 10.0f + pr.x;
        float cy = lc.y * pr.w / 10.0f + pr.y;
        float w  = expf(lc.z / 5.0f) * pr.z;
        float h  = expf(lc.w / 5.0f) * pr.w;
        ((float4*)dec)[(size_t)b * P + p] =
            make_float4(cx - w * 0.5f, cy - h * 0.5f, cx + w * 0.5f, cy + h * 0.5f);
    }
    __syncthreads();

    if (tid < nrows) {
        const float* row = &tile[tid * C];
        float m = row[0];
        for (int cc = 1; cc < C; ++cc) m = fmaxf(m, row[cc]);
        float ss = 0.f;
        for (int cc = 0; cc < C; ++cc) ss += expf(row[cc] - m);
        mrow[tid] = m; srow[tid] = ss;
    }
    __syncthreads();

    for (int idx = tid; idx < 64 * NC; idx += 256) {
        int r  = idx & 63;
        int cc = idx >> 6;
        if (r < nrows) {
            float v = expf(tile[r * C + cc + 1] - mrow[r]) / srow[r];
            probs_t[((size_t)(b * NC + cc)) * P + p0 + r] = v;
        }
    }
}

// ------- Kernel 2: fused per (class,image) top-400 select + sort + IoU + NMS scan -------
// Round-15 kernel + fused stage/level-0 histogram: the staging loop already
// holds each key in a register, so it feeds the level-0 bins directly
// (bin = skey >> 22 == (k >> 54) & 1023); the -1 flood is register-counted
// per wave and flushed once to bin INV32 >> 22 (identical to the bulk path).
__global__ __launch_bounds__(512) void select_nms_kernel(
    const float* __restrict__ dec, const float* __restrict__ probs_t,
    float* __restrict__ cand_sc, float* __restrict__ cand_bx,
    int P, int NC)
{
    const int c = blockIdx.x, b = blockIdx.y;
    const int tid = threadIdx.x;
    const int lane = tid & 63;
    const int wv = tid >> 6;
    const int T = 512;

    __shared__ alignas(16) char bufA[8736 * 4];
    u32* skey = (u32*)bufA;
    u64* inw  = (u64*)bufA;                       // [w][r][lane] column words, [0, 25088)
    float4* cbox = (float4*)(bufA + 25088);       // 448 * 16 B = [25088, 32256)
    __shared__ u64 cand[512];                     // hist[1024] aliases cand
    u32* hist = (u32*)cand;
    __shared__ u64 validm[7], keepm[7];
    __shared__ SelSt st;
    __shared__ int sh_cnt;

    const float* ps = probs_t + ((size_t)(b * NC + c)) * P;

    // ---- zero level-0 histogram, then stage keys + count bins in one pass ----
    hist[tid] = 0u; hist[tid + 512] = 0u;
    if (tid == 0) sh_cnt = 0;
    __syncthreads();

    u32 bulkCnt0 = 0;
    int P4 = P >> 2;
    for (int i = tid; i < P4; i += T) {
        float4 f4 = ((const float4*)ps)[i];
        u32 k0 = f32_key(f4.x > MIN_SCORE ? f4.x : -1.0f);
        u32 k1 = f32_key(f4.y > MIN_SCORE ? f4.y : -1.0f);
        u32 k2 = f32_key(f4.z > MIN_SCORE ? f4.z : -1.0f);
        u32 k3 = f32_key(f4.w > MIN_SCORE ? f4.w : -1.0f);
        skey[i*4+0] = k0; skey[i*4+1] = k1; skey[i*4+2] = k2; skey[i*4+3] = k3;
        if (k0 != INV32) atomicAdd(&hist[k0 >> 22], 1u); else ++bulkCnt0;
        if (k1 != INV32) atomicAdd(&hist[k1 >> 22], 1u); else ++bulkCnt0;
        if (k2 != INV32) atomicAdd(&hist[k2 >> 22], 1u); else ++bulkCnt0;
        if (k3 != INV32) atomicAdd(&hist[k3 >> 22], 1u); else ++bulkCnt0;
    }
    for (int i = (P4 << 2) + tid; i < P; i += T) {
        float f = ps[i];
        u32 k0 = f32_key(f > MIN_SCORE ? f : -1.0f);
        skey[i] = k0;
        if (k0 != INV32) atomicAdd(&hist[k0 >> 22], 1u); else ++bulkCnt0;
    }
    #pragma unroll
    for (int off = 32; off > 0; off >>= 1) bulkCnt0 += __shfl_down(bulkCnt0, off, 64);
    if (lane == 0 && bulkCnt0) atomicAdd(&hist[INV32 >> 22], bulkCnt0);
    __syncthreads();

    // ---- exact top-400 threshold (level-0 prefilled) ----
    hist_select64<512, true>([&](int i, u64& k) {
                                 k = ((u64)skey[i] << 32) | (u64)(u32)(~(u32)i);
                                 return true;
                             },
                             P, WPRE, 512, (((u64)INV32) << 32) | 0xFFFFFFFFull,
                             tid, hist, &st);
    const u64 thr = st.thr;

    // ---- compact keys >= thr (count == st.nge <= 512) ----
    for (int i = tid; i < P; i += T) {
        u64 k = ((u64)skey[i] << 32) | (u64)(u32)(~(u32)i);
        if (k >= thr) {
            int pos = atomicAdd(&sh_cnt, 1);
            if (pos < 512) cand[pos] = k;
        }
    }
    __syncthreads();                    // last read of skey is above
    const int cnt = sh_cnt;             // in [400, 512]
    u64 v = (tid < cnt) ? cand[tid] : 0ull;

    // ---- register bitonic sort 512 desc: shfl within wave, LDS for j>=64 ----
    for (int k = 2; k <= 512; k <<= 1) {
        for (int j = k >> 1; j > 0; j >>= 1) {
            u64 p;
            if (j < 64) {
                p = __shfl_xor(v, j, 64);
            } else {
                __syncthreads();
                cand[tid] = v;
                __syncthreads();
                p = cand[tid ^ j];
            }
            bool takeMax = (((tid & k) == 0) == ((tid & j) == 0));
            v = takeMax ? (v > p ? v : p) : (v > p ? p : v);
        }
    }
    __syncthreads();

    // ---- unpack rank-tid candidate into SoA (skey region is dead) ----
    float4 mybox = make_float4(0.f, 0.f, 0.f, 0.f);
    float myval = -1.0f;
    if (tid < 448) {
        if (tid < WPRE) {
            myval = key_f32((u32)(v >> 32));
            int p = (int)(~(u32)v);
            mybox = ((const float4*)dec)[(size_t)b * P + p];
        }
        cbox[tid] = mybox;
        u64 mk = __ballot(myval > MIN_SCORE);
        if (lane == 0) validm[tid >> 6] = mk;
    }
    __syncthreads();

    // ---- column-word IoU matrix: 28 upper-triangle tiles over 8 waves (frozen) ----
    for (int tt = wv; tt < 28; tt += 8) {
        int r = 0, base = 0;
        while (tt - base >= 7 - r) { base += 7 - r; ++r; }
        int w = r + (tt - base);
        int j = (w << 6) + lane;
        float4 bj = cbox[j];
        float aj = (bj.z - bj.x) * (bj.w - bj.y);
        const int i0 = r << 6;
        u32 acc0 = 0u, acc1 = 0u;
        #pragma unroll 16
        for (int q = 0; q < 32; ++q) {
            int i = i0 + q;
            float4 bi = cbox[i];
            float ai = (bi.z - bi.x) * (bi.w - bi.y);
            float lx = fmaxf(bi.x, bj.x);
            float ly = fmaxf(bi.y, bj.y);
            float rx = fminf(bi.z, bj.z);
            float ry = fminf(bi.w, bj.w);
            float ww = fmaxf(rx - lx, 0.f);
            float hh = fmaxf(ry - ly, 0.f);
            float inter = ww * hh;
            float uniC = fmaxf((ai + aj) - inter, 1e-10f);
            bool pred = (double)inter > IOU_MID * (double)uniC;
            acc0 |= pred ? (1u << q) : 0u;
        }
        #pragma unroll 16
        for (int q = 0; q < 32; ++q) {
            int i = i0 + 32 + q;
            float4 bi = cbox[i];
            float ai = (bi.z - bi.x) * (bi.w - bi.y);
            float lx = fmaxf(bi.x, bj.x);
            float ly = fmaxf(bi.y, bj.y);
            float rx = fminf(bi.z, bj.z);
            float ry = fminf(bi.w, bj.w);
            float ww = fmaxf(rx - lx, 0.f);
            float hh = fmaxf(ry - ly, 0.f);
            float inter = ww * hh;
            float uniC = fmaxf((ai + aj) - inter, 1e-10f);
            bool pred = (double)inter > IOU_MID * (double)uniC;
            acc1 |= pred ? (1u << q) : 0u;
        }
        inw[(w * 7 + r) * 64 + lane] = ((u64)acc1 << 32) | acc0;
    }
    __syncthreads();

    // ---- single-wave hierarchical scan, zero barriers inside ----
    if (wv == 0) {
        u64 keep[7];
        #pragma unroll
        for (int w2 = 0; w2 < 7; ++w2) {
            bool alive = ((validm[w2] >> lane) & 1ull) != 0;
            #pragma unroll
            for (int r = 0; r < w2; ++r) {
                u64 inr = inw[(w2 * 7 + r) * 64 + lane];
                alive = alive && ((inr & keep[r]) == 0ull);
            }
            u64 in_self = inw[(w2 * 7 + w2) * 64 + lane];
            u64 inmask = in_self & ((1ull << lane) - 1ull);
            u64 mm = inmask;
            #pragma unroll
            for (int off = 32; off; off >>= 1) mm |= __shfl_xor(mm, off, 64);
            while (mm) {
                int t = __builtin_ctzll(mm);
                mm &= mm - 1ull;
                u64 am = __ballot(alive);
                if ((am >> t) & 1ull)
                    alive = alive && (((inmask >> t) & 1ull) == 0ull);
            }
            u64 fin = __ballot(alive);
            keep[w2] = fin;
            if (lane == 0) keepm[w2] = fin;
        }
    }
    __syncthreads();

    if (tid < WPRE) {
        bool keep = (keepm[tid >> 6] >> (tid & 63)) & 1ull;
        cand_sc[((size_t)(b * NC + c)) * WPRE + tid] = keep ? myval : -1.0f;
        ((float4*)cand_bx)[((size_t)(b * NC + c)) * WPRE + tid] = mybox;
    }
}

// ---------------- Kernel 3a: per (image, class-group) exact top-200 ----------------
__global__ __launch_bounds__(512) void topkA_kernel(
    const float* __restrict__ cand_sc, u64* __restrict__ wsA,
    int NC, int TOPK, int GS, int NG)
{
    const int g = blockIdx.x, b = blockIdx.y;
    const int tid = threadIdx.x;
    const int T = 512;
    const int N = GS;
    const u32 fbase = (u32)(g * GS);

    __shared__ u32 hist[1024];
    __shared__ SelSt st;
    __shared__ int sh_cnt;

    const float* s = cand_sc + (size_t)b * NC * WPRE + (size_t)g * GS;
    u64* outg = wsA + (size_t)(b * NG + g) * 256;

    if (tid == 0) sh_cnt = 0;
    __syncthreads();

    hist_select64<512, false>([&](int i, u64& k) {
                                  k = ((u64)f32_key(s[i]) << 32) | (u64)(u32)(~(fbase + (u32)i));
                                  return true;
                              },
                              N, TOPK, 256,
                              (((u64)INV32) << 32) | (u64)(u32)(~fbase),
                              tid, hist, &st);
    const u64 thr = st.thr;

    for (int i = tid; i < N; i += T) {
        u64 k = ((u64)f32_key(s[i]) << 32) | (u64)(u32)(~(fbase + (u32)i));
        if (k >= thr) {
            int pos = atomicAdd(&sh_cnt, 1);
            if (pos < 256) outg[pos] = k;
        }
    }
    __syncthreads();
    int cnt = sh_cnt;
    if (tid < 256 && tid >= cnt) outg[tid] = 0ull;
}

// ---------------- Kernel 3b: merge groups, exact top-200, emit ----------------
__global__ __launch_bounds__(256) void topkB_kernel(
    const u64* __restrict__ wsA, const float* __restrict__ cand_bx,
    float* __restrict__ out, int NC, int TOPK, int B, int NG)
{
    const int b = blockIdx.x;
    const int tid = threadIdx.x;
    const int T = 256;
    const int N = NG * 256;

    __shared__ u64 keys[2560];
    __shared__ u32 hist[1024];
    u64* cand = (u64*)hist;
    __shared__ SelSt st;
    __shared__ int sh_cnt;

    const u64* src = wsA + (size_t)b * N;
    for (int i = tid; i < N; i += T) keys[i] = src[i];
    if (tid == 0) sh_cnt = 0;
    __syncthreads();

    hist_select64<256, false>([&](int i, u64& k) { k = keys[i]; return true; },
                              N, TOPK, 256, (((u64)INV32) << 32) | 0xFFFFFFFFull,
                              tid, hist, &st);
    const u64 thr = st.thr;

    for (int i = tid; i < N; i += T) {
        u64 k = keys[i];
        if (k >= thr) {
            int pos = atomicAdd(&sh_cnt, 1);
            if (pos < 256) cand[pos] = k;
        }
    }
    __syncthreads();
    int cnt = sh_cnt;
    u64 v = (tid < cnt) ? cand[tid] : 0ull;

    for (int k = 2; k <= 256; k <<= 1) {
        for (int j = k >> 1; j > 0; j >>= 1) {
            u64 p;
            if (j < 64) {
                p = __shfl_xor(v, j, 64);
            } else {
                __syncthreads();
                cand[tid] = v;
                __syncthreads();
                p = cand[tid ^ j];
            }
            bool takeMax = (((tid & k) == 0) == ((tid & j) == 0));
            v = takeMax ? (v > p ? v : p) : (v > p ? p : v);
        }
    }

    if (tid < TOPK) {
        float sc = key_f32((u32)(v >> 32));
        int flat = (int)(~(u32)v);
        int cls = flat / WPRE;
        float4 bx = ((const float4*)cand_bx)[(size_t)b * NC * WPRE + flat];
        float* ob = out + ((size_t)(b * TOPK + tid)) * 4;
        ob[0] = bx.x; ob[1] = bx.y; ob[2] = bx.z; ob[3] = bx.w;
        out[(size_t)B * TOPK * 4 + (size_t)b * TOPK + tid] = (float)(cls + 1);
        out[(size_t)B * TOPK * 5 + (size_t)b * TOPK + tid] = sc;
    }
}

extern "C" void kernel_launch(void* const* d_in, const int* in_sizes, int n_in,
                              void* d_out, int out_size, void* d_ws, size_t ws_size,
                              hipStream_t stream) {
    const float* locs   = (const float*)d_in[0];
    const float* scores = (const float*)d_in[1];
    const float* priors = (const float*)d_in[2];

    const int P  = in_sizes[2] / 4;          // 8732
    const int B  = in_sizes[0] / (4 * P);    // 8
    const int C  = in_sizes[1] / (B * P);    // 81
    const int NC = C - 1;                    // 80
    const int TOPK = out_size / (B * 6);     // 200
    const int NG = 10;
    const int GS = (NC * WPRE) / NG;         // 3200

    float* ws      = (float*)d_ws;
    float* dec     = ws;                                    // B*P*4
    float* probs_t = dec + (size_t)B * P * 4;               // B*NC*P
    float* cand_sc = probs_t + (size_t)B * NC * P;          // B*NC*WPRE
    float* cand_bx = cand_sc + (size_t)B * NC * WPRE;       // B*NC*WPRE*4
    u64*   wsA     = (u64*)(cand_bx + (size_t)B * NC * WPRE * 4);  // B*NG*256 u64

    dim3 g1((P + 63) / 64, B);
    decode_softmax_kernel<<<g1, 256, 0, stream>>>(locs, scores, priors, dec, probs_t, P, C, NC);

    dim3 g2(NC, B);
    select_nms_kernel<<<g2, 512, 0, stream>>>(dec, probs_t, cand_sc, cand_bx, P, NC);

    dim3 g3(NG, B);
    topkA_kernel<<<g3, 512, 0, stream>>>(cand_sc, wsA, NC, TOPK, GS, NG);
    topkB_kernel<<<dim3(B), 256, 0, stream>>>(wsA, cand_bx, (float*)d_out, NC, TOPK, B, NG);
}

// Round 18
// 127.801 us; speedup vs baseline: 1.1953x; 1.0046x over previous
//
#include <hip/hip_runtime.h>
#include <cstdint>

typedef unsigned long long u64;
typedef unsigned int u32;

#define WPRE 400
#define MIN_SCORE 0.01f
#define MAX_OVERLAP 0.45f
#define INV32 0x407FFFFFu   // f32_key(-1.0f)

// Exact predicate: fdiv_rn(inter,uniC) > 0.45f  <=>  (double)inter > MID*(double)uniC
// MID = midpoint(0.45f, nextafterf(0.45f,+inf)) = 0x1.CCCCCDp-2 (exact double).
#define IOU_MID 0x1.CCCCCDp-2

__device__ __forceinline__ u32 f32_key(float f) {
    u32 u = __float_as_uint(f);
    return (f >= 0.0f) ? (u | 0x80000000u) : ~u;
}
__device__ __forceinline__ float key_f32(u32 k) {
    return __uint_as_float((k & 0x80000000u) ? (k ^ 0x80000000u) : ~k);
}

struct SelSt {
    u64 prefix, thr;
    int r, above, shift, nge, done;
    u32 wtot[8];
};

// Exact top-K threshold over unique u64 keys (descending) via 1024-bin
// histogram level-descent. bulk: value sharing bits [63:14] with a large
// clump of keys (register-counted, one LDS atomic per wave per pass).
// PRE: level-0 histogram was prefilled by the caller (fused with staging);
// skip zero+count on the first level only. PRE=false compiles to the
// proven round-15 code path.
template <int T, bool PRE, typename KF>
__device__ void hist_select64(KF kf, int N, int K, int CAP, u64 bulk,
                              int tid, u32* hist, SelSt* st)
{
    const int lane = tid & 63;
    const int wv = tid >> 6;
    const int nw = T >> 6;
    constexpr int BPT = 1024 / T;

    if (tid == 0) { st->prefix = 0ull; st->r = K; st->above = 0; st->shift = 54; st->done = 0; }
    __syncthreads();

    while (true) {
        const int shift = st->shift;
        const u64 pref = st->prefix;
        const int r = st->r;
        const int above = st->above;
        const bool lvl0 = (shift == 54);

        if (!(PRE && lvl0)) {
            #pragma unroll
            for (int q = 0; q < BPT; ++q) hist[tid * BPT + q] = 0u;
            __syncthreads();

            const bool useBulk = (bulk != 0ull) && (shift >= 14);
            const u64 bulkHi = bulk >> 14;
            u32 bulkCnt = 0;
            for (int i = tid; i < N; i += T) {
                u64 k;
                if (!kf(i, k)) continue;
                if (!lvl0 && (k >> (shift + 10)) != pref) continue;
                if (useBulk && (k >> 14) == bulkHi) { ++bulkCnt; continue; }
                atomicAdd(&hist[(u32)(k >> shift) & 1023u], 1u);
            }
            if (useBulk) {
                #pragma unroll
                for (int off = 32; off > 0; off >>= 1) bulkCnt += __shfl_down(bulkCnt, off, 64);
                if (lane == 0 && bulkCnt) atomicAdd(&hist[(u32)(bulk >> shift) & 1023u], bulkCnt);
            }
            __syncthreads();
        }

        // block suffix-scan over 1024 bins (thread t owns bins [t*BPT, ...))
        u32 hloc[BPT], Sarr[BPT];
        u32 run = 0;
        #pragma unroll
        for (int q = BPT - 1; q >= 0; --q) {
            hloc[q] = hist[tid * BPT + q];
            run += hloc[q];
            Sarr[q] = run;
        }
        u32 incl = run;
        #pragma unroll
        for (int off = 1; off < 64; off <<= 1) {
            u32 x = __shfl_down(incl, off, 64);
            incl += (lane + off < 64) ? x : 0u;
        }
        if (lane == 0) st->wtot[wv] = incl;
        __syncthreads();
        u32 wa = 0;
        for (int w2 = wv + 1; w2 < nw; ++w2) wa += st->wtot[w2];
        const u32 suffAbove = wa + (incl - run);

        bool found = false; int fb = 0; u32 fSn = 0, fh = 0;
        #pragma unroll
        for (int q = 0; q < BPT; ++q) {
            u32 S = suffAbove + Sarr[q];
            u32 Sn = S - hloc[q];
            if ((int)S >= r && (int)Sn < r) { found = true; fb = tid * BPT + q; fSn = Sn; fh = hloc[q]; }
        }
        __syncthreads();
        if (found) {
            u64 np = (pref << 10) | (u64)(u32)fb;
            int nab = above + (int)fSn;
            int nge = nab + (int)fh;
            st->prefix = np;
            st->r = r - (int)fSn;
            st->above = nab;
            st->nge = nge;
            st->thr = np << shift;
            st->shift = shift - 10;
            st->done = (nge <= CAP) || (shift == 4);
        }
        __syncthreads();
        if (st->done) break;
    }
}

// ---------------- Kernel 1: decode boxes + softmax ----------------
__global__ __launch_bounds__(256) void decode_softmax_kernel(
    const float* __restrict__ locs, const float* __restrict__ scores,
    const float* __restrict__ priors, float* __restrict__ dec,
    float* __restrict__ probs_t, int P, int C, int NC)
{
    __shared__ float tile[64 * 81];
    __shared__ float mrow[64], srow[64];
    const int b  = blockIdx.y;
    const int p0 = blockIdx.x * 64;
    const int tid = threadIdx.x;
    const int nrows = min(64, P - p0);
    const int n = nrows * C;

    const float* src = scores + ((size_t)b * P + p0) * C;
    for (int idx = tid; idx < n; idx += 256) tile[idx] = src[idx];

    if (tid < nrows) {
        int p = p0 + tid;
        float4 lc = ((const float4*)locs)[(size_t)b * P + p];
        float4 pr = ((const float4*)priors)[p];
        float cx = lc.x * pr.z / 10.0f + pr.x;
        float cy = lc.y * pr.w / 10.0f + pr.y;
        float w  = expf(lc.z / 5.0f) * pr.z;
        float h  = expf(lc.w / 5.0f) * pr.w;
        ((float4*)dec)[(size_t)b * P + p] =
            make_float4(cx - w * 0.5f, cy - h * 0.5f, cx + w * 0.5f, cy + h * 0.5f);
    }
    __syncthreads();

    if (tid < nrows) {
        const float* row = &tile[tid * C];
        float m = row[0];
        for (int cc = 1; cc < C; ++cc) m = fmaxf(m, row[cc]);
        float ss = 0.f;
        for (int cc = 0; cc < C; ++cc) ss += expf(row[cc] - m);
        mrow[tid] = m; srow[tid] = ss;
    }
    __syncthreads();

    for (int idx = tid; idx < 64 * NC; idx += 256) {
        int r  = idx & 63;
        int cc = idx >> 6;
        if (r < nrows) {
            float v = expf(tile[r * C + cc + 1] - mrow[r]) / srow[r];
            probs_t[((size_t)(b * NC + cc)) * P + p0 + r] = v;
        }
    }
}

// ------- Kernel 2: fused per (class,image) top-400 select + sort + IoU + NMS scan -------
// Round-15 kernel + fused stage/level-0 histogram: the staging loop already
// holds each key in a register, so it feeds the level-0 bins directly
// (bin = skey >> 22 == (k >> 54) & 1023); the -1 flood is register-counted
// per wave and flushed once to bin INV32 >> 22 (identical to the bulk path).
__global__ __launch_bounds__(512) void select_nms_kernel(
    const float* __restrict__ dec, const float* __restrict__ probs_t,
    float* __restrict__ cand_sc, float* __restrict__ cand_bx,
    int P, int NC)
{
    const int c = blockIdx.x, b = blockIdx.y;
    const int tid = threadIdx.x;
    const int lane = tid & 63;
    const int wv = tid >> 6;
    const int T = 512;

    __shared__ alignas(16) char bufA[8736 * 4];
    u32* skey = (u32*)bufA;
    u64* inw  = (u64*)bufA;                       // [w][r][lane] column words, [0, 25088)
    float4* cbox = (float4*)(bufA + 25088);       // 448 * 16 B = [25088, 32256)
    __shared__ u64 cand[512];                     // hist[1024] aliases cand
    u32* hist = (u32*)cand;
    __shared__ u64 validm[7], keepm[7];
    __shared__ SelSt st;
    __shared__ int sh_cnt;

    const float* ps = probs_t + ((size_t)(b * NC + c)) * P;

    // ---- zero level-0 histogram, then stage keys + count bins in one pass ----
    hist[tid] = 0u; hist[tid + 512] = 0u;
    if (tid == 0) sh_cnt = 0;
    __syncthreads();

    u32 bulkCnt0 = 0;
    int P4 = P >> 2;
    for (int i = tid; i < P4; i += T) {
        float4 f4 = ((const float4*)ps)[i];
        u32 k0 = f32_key(f4.x > MIN_SCORE ? f4.x : -1.0f);
        u32 k1 = f32_key(f4.y > MIN_SCORE ? f4.y : -1.0f);
        u32 k2 = f32_key(f4.z > MIN_SCORE ? f4.z : -1.0f);
        u32 k3 = f32_key(f4.w > MIN_SCORE ? f4.w : -1.0f);
        skey[i*4+0] = k0; skey[i*4+1] = k1; skey[i*4+2] = k2; skey[i*4+3] = k3;
        if (k0 != INV32) atomicAdd(&hist[k0 >> 22], 1u); else ++bulkCnt0;
        if (k1 != INV32) atomicAdd(&hist[k1 >> 22], 1u); else ++bulkCnt0;
        if (k2 != INV32) atomicAdd(&hist[k2 >> 22], 1u); else ++bulkCnt0;
        if (k3 != INV32) atomicAdd(&hist[k3 >> 22], 1u); else ++bulkCnt0;
    }
    for (int i = (P4 << 2) + tid; i < P; i += T) {
        float f = ps[i];
        u32 k0 = f32_key(f > MIN_SCORE ? f : -1.0f);
        skey[i] = k0;
        if (k0 != INV32) atomicAdd(&hist[k0 >> 22], 1u); else ++bulkCnt0;
    }
    #pragma unroll
    for (int off = 32; off > 0; off >>= 1) bulkCnt0 += __shfl_down(bulkCnt0, off, 64);
    if (lane == 0 && bulkCnt0) atomicAdd(&hist[INV32 >> 22], bulkCnt0);
    __syncthreads();

    // ---- exact top-400 threshold (level-0 prefilled) ----
    hist_select64<512, true>([&](int i, u64& k) {
                                 k = ((u64)skey[i] << 32) | (u64)(u32)(~(u32)i);
                                 return true;
                             },
                             P, WPRE, 512, (((u64)INV32) << 32) | 0xFFFFFFFFull,
                             tid, hist, &st);
    const u64 thr = st.thr;

    // ---- compact keys >= thr (count == st.nge <= 512) ----
    for (int i = tid; i < P; i += T) {
        u64 k = ((u64)skey[i] << 32) | (u64)(u32)(~(u32)i);
        if (k >= thr) {
            int pos = atomicAdd(&sh_cnt, 1);
            if (pos < 512) cand[pos] = k;
        }
    }
    __syncthreads();                    // last read of skey is above
    const int cnt = sh_cnt;             // in [400, 512]
    u64 v = (tid < cnt) ? cand[tid] : 0ull;

    // ---- register bitonic sort 512 desc: shfl within wave, LDS for j>=64 ----
    for (int k = 2; k <= 512; k <<= 1) {
        for (int j = k >> 1; j > 0; j >>= 1) {
            u64 p;
            if (j < 64) {
                p = __shfl_xor(v, j, 64);
            } else {
                __syncthreads();
                cand[tid] = v;
                __syncthreads();
                p = cand[tid ^ j];
            }
            bool takeMax = (((tid & k) == 0) == ((tid & j) == 0));
            v = takeMax ? (v > p ? v : p) : (v > p ? p : v);
        }
    }
    __syncthreads();

    // ---- unpack rank-tid candidate into SoA (skey region is dead) ----
    float4 mybox = make_float4(0.f, 0.f, 0.f, 0.f);
    float myval = -1.0f;
    if (tid < 448) {
        if (tid < WPRE) {
            myval = key_f32((u32)(v >> 32));
            int p = (int)(~(u32)v);
            mybox = ((const float4*)dec)[(size_t)b * P + p];
        }
        cbox[tid] = mybox;
        u64 mk = __ballot(myval > MIN_SCORE);
        if (lane == 0) validm[tid >> 6] = mk;
    }
    __syncthreads();

    // ---- column-word IoU matrix: 28 upper-triangle tiles over 8 waves (frozen) ----
    for (int tt = wv; tt < 28; tt += 8) {
        int r = 0, base = 0;
        while (tt - base >= 7 - r) { base += 7 - r; ++r; }
        int w = r + (tt - base);
        int j = (w << 6) + lane;
        float4 bj = cbox[j];
        float aj = (bj.z - bj.x) * (bj.w - bj.y);
        const int i0 = r << 6;
        u32 acc0 = 0u, acc1 = 0u;
        #pragma unroll 16
        for (int q = 0; q < 32; ++q) {
            int i = i0 + q;
            float4 bi = cbox[i];
            float ai = (bi.z - bi.x) * (bi.w - bi.y);
            float lx = fmaxf(bi.x, bj.x);
            float ly = fmaxf(bi.y, bj.y);
            float rx = fminf(bi.z, bj.z);
            float ry = fminf(bi.w, bj.w);
            float ww = fmaxf(rx - lx, 0.f);
            float hh = fmaxf(ry - ly, 0.f);
            float inter = ww * hh;
            float uniC = fmaxf((ai + aj) - inter, 1e-10f);
            bool pred = (double)inter > IOU_MID * (double)uniC;
            acc0 |= pred ? (1u << q) : 0u;
        }
        #pragma unroll 16
        for (int q = 0; q < 32; ++q) {
            int i = i0 + 32 + q;
            float4 bi = cbox[i];
            float ai = (bi.z - bi.x) * (bi.w - bi.y);
            float lx = fmaxf(bi.x, bj.x);
            float ly = fmaxf(bi.y, bj.y);
            float rx = fminf(bi.z, bj.z);
            float ry = fminf(bi.w, bj.w);
            float ww = fmaxf(rx - lx, 0.f);
            float hh = fmaxf(ry - ly, 0.f);
            float inter = ww * hh;
            float uniC = fmaxf((ai + aj) - inter, 1e-10f);
            bool pred = (double)inter > IOU_MID * (double)uniC;
            acc1 |= pred ? (1u << q) : 0u;
        }
        inw[(w * 7 + r) * 64 + lane] = ((u64)acc1 << 32) | acc0;
    }
    __syncthreads();

    // ---- single-wave hierarchical scan, zero barriers inside ----
    if (wv == 0) {
        u64 keep[7];
        #pragma unroll
        for (int w2 = 0; w2 < 7; ++w2) {
            bool alive = ((validm[w2] >> lane) & 1ull) != 0;
            #pragma unroll
            for (int r = 0; r < w2; ++r) {
                u64 inr = inw[(w2 * 7 + r) * 64 + lane];
                alive = alive && ((inr & keep[r]) == 0ull);
            }
            u64 in_self = inw[(w2 * 7 + w2) * 64 + lane];
            u64 inmask = in_self & ((1ull << lane) - 1ull);
            u64 mm = inmask;
            #pragma unroll
            for (int off = 32; off; off >>= 1) mm |= __shfl_xor(mm, off, 64);
            while (mm) {
                int t = __builtin_ctzll(mm);
                mm &= mm - 1ull;
                u64 am = __ballot(alive);
                if ((am >> t) & 1ull)
                    alive = alive && (((inmask >> t) & 1ull) == 0ull);
            }
            u64 fin = __ballot(alive);
            keep[w2] = fin;
            if (lane == 0) keepm[w2] = fin;
        }
    }
    __syncthreads();

    if (tid < WPRE) {
        bool keep = (keepm[tid >> 6] >> (tid & 63)) & 1ull;
        cand_sc[((size_t)(b * NC + c)) * WPRE + tid] = keep ? myval : -1.0f;
        ((float4*)cand_bx)[((size_t)(b * NC + c)) * WPRE + tid] = mybox;
    }
}

// ---------------- Kernel 3a: per (image, class-group) exact top-200 ----------------
__global__ __launch_bounds__(512) void topkA_kernel(
    const float* __restrict__ cand_sc, u64* __restrict__ wsA,
    int NC, int TOPK, int GS, int NG)
{
    const int g = blockIdx.x, b = blockIdx.y;
    const int tid = threadIdx.x;
    const int T = 512;
    const int N = GS;
    const u32 fbase = (u32)(g * GS);

    __shared__ u32 hist[1024];
    __shared__ SelSt st;
    __shared__ int sh_cnt;

    const float* s = cand_sc + (size_t)b * NC * WPRE + (size_t)g * GS;
    u64* outg = wsA + (size_t)(b * NG + g) * 256;

    if (tid == 0) sh_cnt = 0;
    __syncthreads();

    hist_select64<512, false>([&](int i, u64& k) {
                                  k = ((u64)f32_key(s[i]) << 32) | (u64)(u32)(~(fbase + (u32)i));
                                  return true;
                              },
                              N, TOPK, 256,
                              (((u64)INV32) << 32) | (u64)(u32)(~fbase),
                              tid, hist, &st);
    const u64 thr = st.thr;

    for (int i = tid; i < N; i += T) {
        u64 k = ((u64)f32_key(s[i]) << 32) | (u64)(u32)(~(fbase + (u32)i));
        if (k >= thr) {
            int pos = atomicAdd(&sh_cnt, 1);
            if (pos < 256) outg[pos] = k;
        }
    }
    __syncthreads();
    int cnt = sh_cnt;
    if (tid < 256 && tid >= cnt) outg[tid] = 0ull;
}

// ---------------- Kernel 3b: merge groups, exact top-200, emit ----------------
__global__ __launch_bounds__(256) void topkB_kernel(
    const u64* __restrict__ wsA, const float* __restrict__ cand_bx,
    float* __restrict__ out, int NC, int TOPK, int B, int NG)
{
    const int b = blockIdx.x;
    const int tid = threadIdx.x;
    const int T = 256;
    const int N = NG * 256;

    __shared__ u64 keys[2560];
    __shared__ u32 hist[1024];
    u64* cand = (u64*)hist;
    __shared__ SelSt st;
    __shared__ int sh_cnt;

    const u64* src = wsA + (size_t)b * N;
    for (int i = tid; i < N; i += T) keys[i] = src[i];
    if (tid == 0) sh_cnt = 0;
    __syncthreads();

    hist_select64<256, false>([&](int i, u64& k) { k = keys[i]; return true; },
                              N, TOPK, 256, (((u64)INV32) << 32) | 0xFFFFFFFFull,
                              tid, hist, &st);
    const u64 thr = st.thr;

    for (int i = tid; i < N; i += T) {
        u64 k = keys[i];
        if (k >= thr) {
            int pos = atomicAdd(&sh_cnt, 1);
            if (pos < 256) cand[pos] = k;
        }
    }
    __syncthreads();
    int cnt = sh_cnt;
    u64 v = (tid < cnt) ? cand[tid] : 0ull;

    for (int k = 2; k <= 256; k <<= 1) {
        for (int j = k >> 1; j > 0; j >>= 1) {
            u64 p;
            if (j < 64) {
                p = __shfl_xor(v, j, 64);
            } else {
                __syncthreads();
                cand[tid] = v;
                __syncthreads();
                p = cand[tid ^ j];
            }
            bool takeMax = (((tid & k) == 0) == ((tid & j) == 0));
            v = takeMax ? (v > p ? v : p) : (v > p ? p : v);
        }
    }

    if (tid < TOPK) {
        float sc = key_f32((u32)(v >> 32));
        int flat = (int)(~(u32)v);
        int cls = flat / WPRE;
        float4 bx = ((const float4*)cand_bx)[(size_t)b * NC * WPRE + flat];
        float* ob = out + ((size_t)(b * TOPK + tid)) * 4;
        ob[0] = bx.x; ob[1] = bx.y; ob[2] = bx.z; ob[3] = bx.w;
        out[(size_t)B * TOPK * 4 + (size_t)b * TOPK + tid] = (float)(cls + 1);
        out[(size_t)B * TOPK * 5 + (size_t)b * TOPK + tid] = sc;
    }
}

extern "C" void kernel_launch(void* const* d_in, const int* in_sizes, int n_in,
                              void* d_out, int out_size, void* d_ws, size_t ws_size,
                              hipStream_t stream) {
    const float* locs   = (const float*)d_in[0];
    const float* scores = (const float*)d_in[1];
    const float* priors = (const float*)d_in[2];

    const int P  = in_sizes[2] / 4;          // 8732
    const int B  = in_sizes[0] / (4 * P);    // 8
    const int C  = in_sizes[1] / (B * P);    // 81
    const int NC = C - 1;                    // 80
    const int TOPK = out_size / (B * 6);     // 200
    const int NG = 10;
    const int GS = (NC * WPRE) / NG;         // 3200

    float* ws      = (float*)d_ws;
    float* dec     = ws;                                    // B*P*4
    float* probs_t = dec + (size_t)B * P * 4;               // B*NC*P
    float* cand_sc = probs_t + (size_t)B * NC * P;          // B*NC*WPRE
    float* cand_bx = cand_sc + (size_t)B * NC * WPRE;       // B*NC*WPRE*4
    u64*   wsA     = (u64*)(cand_bx + (size_t)B * NC * WPRE * 4);  // B*NG*256 u64

    dim3 g1((P + 63) / 64, B);
    decode_softmax_kernel<<<g1, 256, 0, stream>>>(locs, scores, priors, dec, probs_t, P, C, NC);

    dim3 g2(NC, B);
    select_nms_kernel<<<g2, 512, 0, stream>>>(dec, probs_t, cand_sc, cand_bx, P, NC);

    dim3 g3(NG, B);
    topkA_kernel<<<g3, 512, 0, stream>>>(cand_sc, wsA, NC, TOPK, GS, NG);
    topkB_kernel<<<dim3(B), 256, 0, stream>>>(wsA, cand_bx, (float*)d_out, NC, TOPK, B, NG);
}